// Round 22
// baseline (348.296 us; speedup 1.0000x reference)
//
#include <hip/hip_runtime.h>
#include <stdint.h>

// GeneDynamics: out = -x + (A @ x^2) / (x^2 + 1)
// v18: v17 (1 KiB A-bursts, 4-rows/thread, NT) + bf16 X tile at proper
//      amortization: X reads 32->16 b128/thread-chunk (LDS 102->61 us),
//      tX 16->8 KiB -> 40 KiB -> 4 blocks/CU (16 waves). waves_per_eu(1,4).

#define NN 16384
#define DIM 16
#define TPB 256                // 4 waves
#define ROWS 32                // rows per block
#define NRB 512                // NN / ROWS
#define KSPLIT 2
#define KRANGE 8192            // NN / KSPLIT
#define KC 256                 // k per chunk (1 KiB per row per chunk)
#define NCH 32                 // KRANGE / KC

__device__ __forceinline__ uint32_t f2bf(float f) {   // round-to-nearest-even
    uint32_t u = __float_as_uint(f);
    return (u + 0x7fffu + ((u >> 16) & 1u)) >> 16;
}

// prep: out = -x ; inv = 1/(x^2+1) ; xhb[k] = 8 u32 of packed bf16(x^2) pairs
__global__ __launch_bounds__(256) void prep_kernel(const float* __restrict__ x,
                                                   float* __restrict__ out,
                                                   uint32_t* __restrict__ xhb,
                                                   float* __restrict__ inv) {
    int i = blockIdx.x * 256 + threadIdx.x;            // row 0..16383
    const float4* xr = reinterpret_cast<const float4*>(x + (size_t)i * DIM);
    float4* orow = reinterpret_cast<float4*>(out + (size_t)i * DIM);
    float4* irow = reinterpret_cast<float4*>(inv + (size_t)i * DIM);
    uint32_t* xb = xhb + (size_t)i * 8;
    #pragma unroll
    for (int v = 0; v < 4; ++v) {
        float4 xv = xr[v];
        orow[v] = make_float4(-xv.x, -xv.y, -xv.z, -xv.w);
        float4 h = make_float4(xv.x * xv.x, xv.y * xv.y, xv.z * xv.z, xv.w * xv.w);
        irow[v] = make_float4(1.f / (h.x + 1.f), 1.f / (h.y + 1.f),
                              1.f / (h.z + 1.f), 1.f / (h.w + 1.f));
        xb[2 * v]     = f2bf(h.x) | (f2bf(h.y) << 16);   // d=4v, 4v+1
        xb[2 * v + 1] = f2bf(h.z) | (f2bf(h.w) << 16);   // d=4v+2, 4v+3
    }
}

__device__ __forceinline__ void gload_lds16(const void* g, void* l, int nt) {
    if (nt)
        __builtin_amdgcn_global_load_lds(
            (const __attribute__((address_space(1))) void*)g,
            (__attribute__((address_space(3))) void*)l, 16, 0, 2 /*NT*/);
    else
        __builtin_amdgcn_global_load_lds(
            (const __attribute__((address_space(1))) void*)g,
            (__attribute__((address_space(3))) void*)l, 16, 0, 0);
}

__device__ __forceinline__ float4 shfl_xor4(float4 v, int mask) {
    return make_float4(__shfl_xor(v.x, mask), __shfl_xor(v.y, mask),
                       __shfl_xor(v.z, mask), __shfl_xor(v.w, mask));
}

__global__ __launch_bounds__(TPB)
__attribute__((amdgpu_waves_per_eu(1, 4)))     // 128-VGPR budget: spill-proof
void agg_kernel(const float* __restrict__ A,
                const uint32_t* __restrict__ xhb,
                const float* __restrict__ inv,
                float* __restrict__ out) {
    // tA[32 rows][256 k] f32: row r holds logical f4-slot s at phys s^(r&7)
    //   (involution carried on per-lane SOURCE address; dest lane-linear).
    // tXb[256 k][8 u32]: plain linear bf16 pairs (compute reads are 2-addr
    //   per 16-lane phase on one 4-bank span -> 2-way = free).
    __shared__ float    tA[ROWS * KC];   // 32 KiB
    __shared__ uint32_t tXb[KC * 8];     // 8 KiB   (40 KiB -> 4 blocks/CU)

    const int tid = threadIdx.x;
    const int l = tid & 63, w = tid >> 6;
    const int m8 = l & 7, q8 = l >> 3;        // 4 rows/thread, 8 k-phases
    const int rb = blockIdx.x & (NRB - 1);
    const int ks = blockIdx.x >> 9;
    const int r0 = rb * ROWS;
    const size_t k0 = (size_t)ks * KRANGE;

    // ---- A staging: wave w, instr i (0..7) -> row 8w+i; lane l loads logical
    //      f4-slot l^(i&7) of that row's 1 KiB chunk segment ----
    const float* Ab = A + (size_t)(r0 + 8 * w) * NN + k0;
    int aoff[8];
    #pragma unroll
    for (int i = 0; i < 8; ++i) aoff[i] = 4 * (l ^ (i & 7));

    // ---- X staging: instr j (0..1): u32s [(2w+j)*256, +256), 16 B/lane ----
    const uint32_t* Xc = xhb + k0 * 8;
    int xoff[2];
    #pragma unroll
    for (int j = 0; j < 2; ++j) xoff[j] = (2 * w + j) * 256 + 4 * l;

    // ---- compute-side indices (loop-invariant) ----
    // thread (w,q8,m8): rows m8+8j (j=0..3), k = 64w + 8q8 + 4b + e
    int rA[4][2];
    #pragma unroll
    for (int j = 0; j < 4; ++j)
        #pragma unroll
        for (int b = 0; b < 2; ++b)
            rA[j][b] = (m8 + 8 * j) * KC + 4 * ((16 * w + 2 * q8 + b) ^ m8);
    const int KB = (64 * w + 8 * q8) * 8;      // u32 base of this thread's k-window

    float4 acc[4][4];   // [row j][d-quad v] = 64 floats
    #pragma unroll
    for (int j = 0; j < 4; ++j)
        #pragma unroll
        for (int v = 0; v < 4; ++v) acc[j][v] = make_float4(0.f, 0.f, 0.f, 0.f);

    for (int t = 0; t < NCH; ++t) {
        __syncthreads();                 // tile t-1 fully consumed by all waves
        // ---- STAGE(t): 8 A-instrs (1 KiB contiguous, NT) + 2 X-instrs ----
        {
            const float* sA = Ab + (size_t)t * KC;
            #pragma unroll
            for (int i = 0; i < 8; ++i)
                gload_lds16(sA + (size_t)i * NN + aoff[i], &tA[(8 * w + i) * KC], 1);
            const uint32_t* sX = Xc + (size_t)t * (KC * 8);
            #pragma unroll
            for (int j = 0; j < 2; ++j)
                gload_lds16(sX + xoff[j], &tXb[(2 * w + j) * 256], 0);
        }
        __syncthreads();                 // drain: tile t resident
        // ---- COMPUTE(t): 8 A + 16 X b128 reads, 64 unpack, 512 FMA ----
        #pragma unroll
        for (int b = 0; b < 2; ++b) {
            float4 ar[4];
            #pragma unroll
            for (int j = 0; j < 4; ++j)
                ar[j] = *reinterpret_cast<const float4*>(&tA[rA[j][b]]);
            #pragma unroll
            for (int e = 0; e < 4; ++e) {
                const int kb = KB + (4 * b + e) * 8;       // unroll-const offset
                // ---- d = 0..7 ----
                {
                    uint4 X0 = *reinterpret_cast<const uint4*>(&tXb[kb]);
                    const uint32_t* u = &X0.x;
                    float xq[8];
                    #pragma unroll
                    for (int jj = 0; jj < 4; ++jj) {
                        xq[2 * jj]     = __uint_as_float(u[jj] << 16);
                        xq[2 * jj + 1] = __uint_as_float(u[jj] & 0xffff0000u);
                    }
                    #pragma unroll
                    for (int j = 0; j < 4; ++j) {
                        const float a = (&ar[j].x)[e];
                        acc[j][0].x += a * xq[0]; acc[j][0].y += a * xq[1];
                        acc[j][0].z += a * xq[2]; acc[j][0].w += a * xq[3];
                        acc[j][1].x += a * xq[4]; acc[j][1].y += a * xq[5];
                        acc[j][1].z += a * xq[6]; acc[j][1].w += a * xq[7];
                    }
                }
                // ---- d = 8..15 ----
                {
                    uint4 X1 = *reinterpret_cast<const uint4*>(&tXb[kb + 4]);
                    const uint32_t* u = &X1.x;
                    float xq[8];
                    #pragma unroll
                    for (int jj = 0; jj < 4; ++jj) {
                        xq[2 * jj]     = __uint_as_float(u[jj] << 16);
                        xq[2 * jj + 1] = __uint_as_float(u[jj] & 0xffff0000u);
                    }
                    #pragma unroll
                    for (int j = 0; j < 4; ++j) {
                        const float a = (&ar[j].x)[e];
                        acc[j][2].x += a * xq[0]; acc[j][2].y += a * xq[1];
                        acc[j][2].z += a * xq[2]; acc[j][2].w += a * xq[3];
                        acc[j][3].x += a * xq[4]; acc[j][3].y += a * xq[5];
                        acc[j][3].z += a * xq[6]; acc[j][3].w += a * xq[7];
                    }
                }
            }
        }
    }

    // ---- 3-stage half-exchange butterfly over the 8 k-phases q8 ----
    // flat idx f = j*16 + d; final: lane holds f in [8*q8, 8*q8+8)
    {
        const int b2 = (q8 >> 2) & 1, b1 = (q8 >> 1) & 1, b0 = q8 & 1;
        #pragma unroll
        for (int j = 0; j < 2; ++j)
            #pragma unroll
            for (int v = 0; v < 4; ++v) {
                float4 send = b2 ? acc[j][v] : acc[j + 2][v];
                float4 keep = b2 ? acc[j + 2][v] : acc[j][v];
                float4 r = shfl_xor4(send, 32);
                acc[j][v] = make_float4(keep.x + r.x, keep.y + r.y,
                                        keep.z + r.z, keep.w + r.w);
            }
        #pragma unroll
        for (int v = 0; v < 4; ++v) {
            float4 send = b1 ? acc[0][v] : acc[1][v];
            float4 keep = b1 ? acc[1][v] : acc[0][v];
            float4 r = shfl_xor4(send, 16);
            acc[0][v] = make_float4(keep.x + r.x, keep.y + r.y,
                                    keep.z + r.z, keep.w + r.w);
        }
        #pragma unroll
        for (int v = 0; v < 2; ++v) {
            float4 send = b0 ? acc[0][v] : acc[0][v + 2];
            float4 keep = b0 ? acc[0][v + 2] : acc[0][v];
            float4 r = shfl_xor4(send, 8);
            acc[0][v] = make_float4(keep.x + r.x, keep.y + r.y,
                                    keep.z + r.z, keep.w + r.w);
        }
    }

    // ---- epilogue: lane owns row m8 + 8*(q8>>1), d in [8*(q8&1), +8) ----
    // out += partial * inv (linear in agg -> split-K/wave merge via atomics exact)
    {
        const int R = r0 + m8 + 8 * (q8 >> 1);
        const int d0 = 8 * (q8 & 1);
        const float* ivp = inv + (size_t)R * DIM + d0;
        float* op = out + (size_t)R * DIM + d0;
        float4 iv0 = *reinterpret_cast<const float4*>(ivp);
        float4 iv1 = *reinterpret_cast<const float4*>(ivp + 4);
        atomicAdd(op + 0, acc[0][0].x * iv0.x);
        atomicAdd(op + 1, acc[0][0].y * iv0.y);
        atomicAdd(op + 2, acc[0][0].z * iv0.z);
        atomicAdd(op + 3, acc[0][0].w * iv0.w);
        atomicAdd(op + 4, acc[0][1].x * iv1.x);
        atomicAdd(op + 5, acc[0][1].y * iv1.y);
        atomicAdd(op + 6, acc[0][1].z * iv1.z);
        atomicAdd(op + 7, acc[0][1].w * iv1.w);
    }
}

extern "C" void kernel_launch(void* const* d_in, const int* in_sizes, int n_in,
                              void* d_out, int out_size, void* d_ws, size_t ws_size,
                              hipStream_t stream) {
    const float* A = (const float*)d_in[0];
    const float* x = (const float*)d_in[1];
    float* out = (float*)d_out;
    uint32_t* xhb = (uint32_t*)d_ws;                          // 512 KiB
    float* inv = (float*)((char*)d_ws + 512 * 1024);          // 1 MiB

    prep_kernel<<<NN / 256, 256, 0, stream>>>(x, out, xhb, inv);
    agg_kernel<<<NRB * KSPLIT, TPB, 0, stream>>>(A, xhb, inv, out);
}